// Round 1
// baseline (330.964 us; speedup 1.0000x reference)
//
#include <hip/hip_runtime.h>
#include <hip/hip_bf16.h>

#define B_ 128
#define H_ 1024
#define L_ 60
#define V_ 50257

typedef __attribute__((ext_vector_type(8))) short bf16x8;
typedef __attribute__((ext_vector_type(4))) float f32x4;

__device__ __forceinline__ unsigned short f2bf(float f) {
  union { float f; unsigned u; } v; v.f = f;
  unsigned u = v.u;
  return (unsigned short)((u + 0x7fffu + ((u >> 16) & 1u)) >> 16);
}

// bf16 A-fragment pack position for MFMA 16x16x32: frag ((s*8+bm)*64+lane), elem j
// lane l holds A[row = l&15][k = (l>>4)*8 + j] of subtile (bm, k-step s)
__device__ __forceinline__ size_t packIdx(int b, int k) {
  int s = k >> 5;
  int bm = b >> 4;
  int lane = (b & 15) | (((k >> 3) & 3) << 4);
  return ((size_t)((s * 8 + bm) * 64 + lane) << 3) | (size_t)(k & 7);
}

// ---------------- attention: embed gather, logits, softmax, weighted sum, pack xa ----
__global__ __launch_bounds__(256) void k_attn(
    const int* __restrict__ input, const float* __restrict__ hidden,
    const float* __restrict__ enc, const float* __restrict__ emb,
    const float* __restrict__ attn_W, const float* __restrict__ attn_b,
    unsigned short* __restrict__ aXa, float* __restrict__ attn_out)
{
  __shared__ float sE[H_], sH[H_], sApp[H_];
  __shared__ float sLog[64], sWt[64];
  int b = blockIdx.x;
  int t = threadIdx.x;
  const float* erow = emb + (size_t)input[b] * H_;
  const float* hrow = hidden + (size_t)b * H_;
  for (int i = t; i < H_; i += 256) { sE[i] = erow[i]; sH[i] = hrow[i]; }
  __syncthreads();
  int wv = t >> 6, lane = t & 63;
  for (int l = wv; l < L_; l += 4) {
    const float* wr = attn_W + (size_t)l * (2 * H_);
    float acc = 0.f;
    for (int m = lane; m < H_; m += 64)
      acc += sE[m] * wr[m] + sH[m] * wr[H_ + m];
    #pragma unroll
    for (int off = 32; off; off >>= 1) acc += __shfl_down(acc, off);
    if (lane == 0) sLog[l] = acc + attn_b[l];
  }
  __syncthreads();
  if (wv == 0) {
    float v = (lane < L_) ? sLog[lane] : -1e30f;
    float m = v;
    #pragma unroll
    for (int off = 32; off; off >>= 1) m = fmaxf(m, __shfl_xor(m, off));
    float e = (lane < L_) ? __expf(v - m) : 0.f;
    float s = e;
    #pragma unroll
    for (int off = 32; off; off >>= 1) s += __shfl_xor(s, off);
    float w = e / s;
    if (lane < L_) { sWt[lane] = w; attn_out[b * L_ + lane] = w; }
  }
  __syncthreads();
  const float* eb = enc + (size_t)b * L_ * H_;
  float acc[4] = {0.f, 0.f, 0.f, 0.f};
  for (int l = 0; l < L_; ++l) {
    float wl = sWt[l];
    #pragma unroll
    for (int c = 0; c < 4; ++c)
      acc[c] += wl * eb[l * H_ + t + c * 256];
  }
  #pragma unroll
  for (int c = 0; c < 4; ++c) sApp[t + c * 256] = acc[c];
  __syncthreads();
  for (int k = t; k < 2 * H_; k += 256) {
    float v = (k < H_) ? sE[k] : sApp[k - H_];
    aXa[packIdx(b, k)] = f2bf(v);
  }
}

// ---------------- f32 [B_,K] -> packed bf16 fragments ----------------
__global__ __launch_bounds__(256) void k_pack(
    const float* __restrict__ src, unsigned short* __restrict__ dst, int K)
{
  int idx = blockIdx.x * 256 + threadIdx.x;  // over B_*K
  int b = idx / K, k = idx - b * K;
  dst[packIdx(b, k)] = f2bf(src[idx]);
}

// ---------------- generic MFMA GEMM: C[b,n] = sum_k A[b,k]*W[n,k] ----------------
// A pre-packed bf16 fragments; W row-major f32 [N][K] converted in-register.
// Cpart != null: write split partial [split][B_][N]. else: Cdir[b*ldc+n] = acc + bias.
__global__ __launch_bounds__(256) void k_gemm(
    const unsigned short* __restrict__ Apk, const float* __restrict__ Wt,
    const float* __restrict__ bias, float* __restrict__ Cdir,
    float* __restrict__ Cpart, int K, int N, int ldc, int steps)
{
  int t = threadIdx.x;
  int wv = t >> 6, lane = t & 63;
  int n0 = blockIdx.x * 64;
  int col = n0 + wv * 16 + (lane & 15);
  int gn = (col < N) ? col : (N - 1);
  int kgrp = (lane >> 4) * 8;
  f32x4 acc[8];
  #pragma unroll
  for (int i = 0; i < 8; ++i) acc[i] = (f32x4){0.f, 0.f, 0.f, 0.f};
  int s0 = blockIdx.y * steps;
  const float* wbase = Wt + (size_t)gn * K + kgrp;
  const bf16x8* ap0 = (const bf16x8*)Apk + lane;
  for (int s = s0; s < s0 + steps; ++s) {
    const float* wr = wbase + s * 32;
    float4 b0 = *(const float4*)wr;
    float4 b1 = *(const float4*)(wr + 4);
    bf16x8 bf;
    bf[0] = (short)f2bf(b0.x); bf[1] = (short)f2bf(b0.y);
    bf[2] = (short)f2bf(b0.z); bf[3] = (short)f2bf(b0.w);
    bf[4] = (short)f2bf(b1.x); bf[5] = (short)f2bf(b1.y);
    bf[6] = (short)f2bf(b1.z); bf[7] = (short)f2bf(b1.w);
    const bf16x8* ap = ap0 + (size_t)s * 512;
    #pragma unroll
    for (int bm = 0; bm < 8; ++bm) {
      bf16x8 af = ap[bm * 64];
      acc[bm] = __builtin_amdgcn_mfma_f32_16x16x32_bf16(af, bf, acc[bm], 0, 0, 0);
    }
  }
  int rb = (lane >> 4) * 4;
  if (col < N) {
    if (Cpart) {
      float* dst = Cpart + (size_t)blockIdx.y * B_ * N;
      #pragma unroll
      for (int bm = 0; bm < 8; ++bm)
        #pragma unroll
        for (int r = 0; r < 4; ++r)
          dst[(size_t)(bm * 16 + rb + r) * N + col] = acc[bm][r];
    } else {
      float bv = bias ? bias[col] : 0.f;
      #pragma unroll
      for (int bm = 0; bm < 8; ++bm)
        #pragma unroll
        for (int r = 0; r < 4; ++r)
          Cdir[(size_t)(bm * 16 + rb + r) * ldc + col] = acc[bm][r] + bv;
    }
  }
}

// ---------------- reduce combine partials + bias + relu -> packed x ----------------
__global__ __launch_bounds__(256) void k_reduce_comb(
    const float* __restrict__ parts, const float* __restrict__ bias,
    unsigned short* __restrict__ aX)
{
  int idx = blockIdx.x * 256 + threadIdx.x;  // B_*H_
  int b = idx >> 10, j = idx & (H_ - 1);
  float s = bias[j];
  #pragma unroll
  for (int p = 0; p < 8; ++p) s += parts[(size_t)p * B_ * H_ + idx];
  s = fmaxf(s, 0.f);
  aX[packIdx(b, j)] = f2bf(s);
}

// ---------------- GRU gates from split partials -> h_new (+packed) ----------------
__global__ __launch_bounds__(256) void k_gate(
    const float* __restrict__ giP, const float* __restrict__ ghP,
    const float* __restrict__ b_ih, const float* __restrict__ b_hh,
    const float* __restrict__ hidden, float* __restrict__ hnew,
    unsigned short* __restrict__ aHn)
{
  int idx = blockIdx.x * 256 + threadIdx.x;  // B_*H_
  int b = idx >> 10, j = idx & (H_ - 1);
  size_t base = (size_t)b * 3 * H_;
  float ir = b_ih[j], iz = b_ih[H_ + j], in_ = b_ih[2 * H_ + j];
  float hr = b_hh[j], hz = b_hh[H_ + j], hn = b_hh[2 * H_ + j];
  #pragma unroll
  for (int p = 0; p < 4; ++p) {
    const float* gi = giP + (size_t)p * B_ * 3 * H_ + base;
    const float* gh = ghP + (size_t)p * B_ * 3 * H_ + base;
    ir += gi[j]; iz += gi[H_ + j]; in_ += gi[2 * H_ + j];
    hr += gh[j]; hz += gh[H_ + j]; hn += gh[2 * H_ + j];
  }
  float r = 1.f / (1.f + __expf(-(ir + hr)));
  float z = 1.f / (1.f + __expf(-(iz + hz)));
  float n = tanhf(in_ + r * hn);
  float h = hidden[idx];
  float hv = (1.f - z) * n + z * h;
  hnew[idx] = hv;
  aHn[packIdx(b, j)] = f2bf(hv);
}

// ---------------- in-place log_softmax over V per row ----------------
__global__ __launch_bounds__(256) void k_lsm(float* __restrict__ logits)
{
  __shared__ float red[4], red2[4];
  int b = blockIdx.x, t = threadIdx.x;
  float* row = logits + (size_t)b * V_;
  float m = -1e30f;
  for (int v = t; v < V_; v += 256) m = fmaxf(m, row[v]);
  #pragma unroll
  for (int off = 32; off; off >>= 1) m = fmaxf(m, __shfl_xor(m, off));
  if ((t & 63) == 0) red[t >> 6] = m;
  __syncthreads();
  m = fmaxf(fmaxf(red[0], red[1]), fmaxf(red[2], red[3]));
  float s = 0.f;
  for (int v = t; v < V_; v += 256) s += __expf(row[v] - m);
  #pragma unroll
  for (int off = 32; off; off >>= 1) s += __shfl_xor(s, off);
  if ((t & 63) == 0) red2[t >> 6] = s;
  __syncthreads();
  s = red2[0] + red2[1] + red2[2] + red2[3];
  float c = m + logf(s);
  for (int v = t; v < V_; v += 256) row[v] -= c;
}

extern "C" void kernel_launch(void* const* d_in, const int* in_sizes, int n_in,
                              void* d_out, int out_size, void* d_ws, size_t ws_size,
                              hipStream_t stream)
{
  const int*   input  = (const int*)d_in[0];
  const float* hidden = (const float*)d_in[1];
  const float* enc    = (const float*)d_in[2];
  const float* emb    = (const float*)d_in[3];
  const float* attn_W = (const float*)d_in[4];
  const float* attn_b = (const float*)d_in[5];
  const float* comb_W = (const float*)d_in[6];
  const float* comb_b = (const float*)d_in[7];
  const float* W_ih   = (const float*)d_in[8];
  const float* W_hh   = (const float*)d_in[9];
  const float* b_ih   = (const float*)d_in[10];
  const float* b_hh   = (const float*)d_in[11];
  const float* out_W  = (const float*)d_in[12];
  const float* out_b  = (const float*)d_in[13];

  float* out    = (float*)d_out;
  float* logits = out;                        // [B,V]
  float* hnew   = out + (size_t)B_ * V_;      // [1,B,H]
  float* attnw  = hnew + (size_t)B_ * H_;     // [B,L]

  char* ws = (char*)d_ws;
  unsigned short* aXa = (unsigned short*)(ws);                    // 512 KB (K=2048)
  unsigned short* aH  = (unsigned short*)(ws + (512 << 10));      // 256 KB
  unsigned short* aX  = (unsigned short*)(ws + (768 << 10));      // 256 KB
  unsigned short* aHn = (unsigned short*)(ws + (1024 << 10));     // 256 KB
  float* combP = (float*)(ws + (1280 << 10));                     // 8 * 512 KB
  float* giP   = (float*)(ws + (1280 << 10) + (4 << 20));         // 4 * 1.5 MB
  float* ghP   = (float*)(ws + (1280 << 10) + (10 << 20));        // 4 * 1.5 MB

  // 1. attention + pack [embedded|attn_applied] (K=2048)
  k_attn<<<B_, 256, 0, stream>>>(input, hidden, enc, emb, attn_W, attn_b, aXa, attnw);
  // 2. pack h for W_hh GEMM
  k_pack<<<(B_ * H_) / 256, 256, 0, stream>>>(hidden, aH, H_);
  // 3. combine GEMM (split-K 8)
  k_gemm<<<dim3(H_ / 64, 8), 256, 0, stream>>>(aXa, comb_W, nullptr, nullptr, combP,
                                               2 * H_, H_, H_, 8);
  // 4. reduce + bias + relu -> packed x
  k_reduce_comb<<<(B_ * H_) / 256, 256, 0, stream>>>(combP, comb_b, aX);
  // 5. gi = x @ W_ih^T, gh = h @ W_hh^T (split-K 4)
  k_gemm<<<dim3(3 * H_ / 64, 4), 256, 0, stream>>>(aX, W_ih, nullptr, nullptr, giP,
                                                   H_, 3 * H_, 3 * H_, 8);
  k_gemm<<<dim3(3 * H_ / 64, 4), 256, 0, stream>>>(aH, W_hh, nullptr, nullptr, ghP,
                                                   H_, 3 * H_, 3 * H_, 8);
  // 6. gates -> h_new (out) + packed h_new
  k_gate<<<(B_ * H_) / 256, 256, 0, stream>>>(giP, ghP, b_ih, b_hh, hidden, hnew, aHn);
  // 7. projection: logits = h_new @ out_W^T + out_b  (direct to d_out)
  k_gemm<<<dim3((V_ + 63) / 64, 1), 256, 0, stream>>>(aHn, out_W, out_b, logits, nullptr,
                                                      H_, V_, V_, 32);
  // 8. in-place log_softmax
  k_lsm<<<B_, 256, 0, stream>>>(logits);
}

// Round 2
// 290.893 us; speedup vs baseline: 1.1378x; 1.1378x over previous
//
#include <hip/hip_runtime.h>
#include <hip/hip_bf16.h>

#define B_ 128
#define H_ 1024
#define L_ 60
#define V_ 50257

typedef __attribute__((ext_vector_type(8))) short bf16x8;
typedef __attribute__((ext_vector_type(4))) float f32x4;

__device__ __forceinline__ unsigned short f2bf(float f) {
  union { __hip_bfloat16 h; unsigned short u; } v;
  v.h = __float2bfloat16(f);
  return v.u;
}

__device__ __forceinline__ bf16x8 cvt8(float4 a, float4 b) {
  union { bf16x8 v; __hip_bfloat16 h[8]; } u;
  u.h[0] = __float2bfloat16(a.x); u.h[1] = __float2bfloat16(a.y);
  u.h[2] = __float2bfloat16(a.z); u.h[3] = __float2bfloat16(a.w);
  u.h[4] = __float2bfloat16(b.x); u.h[5] = __float2bfloat16(b.y);
  u.h[6] = __float2bfloat16(b.z); u.h[7] = __float2bfloat16(b.w);
  return u.v;
}

// bf16 A-fragment pack position for MFMA 16x16x32: fragment ((s*8+bm)*64+lane), elem j
// lane l holds A[row = l&15][k = (l>>4)*8 + j] of subtile (bm, k-step s)
__device__ __forceinline__ size_t packIdx(int b, int k) {
  int s = k >> 5;
  int bm = b >> 4;
  int lane = (b & 15) | (((k >> 3) & 3) << 4);
  return ((size_t)((s * 8 + bm) * 64 + lane) << 3) | (size_t)(k & 7);
}

// ------------- attn part 1: embed gather, logits, softmax; pack embedded + h -------------
__global__ __launch_bounds__(256) void k_attn1(
    const int* __restrict__ input, const float* __restrict__ hidden,
    const float* __restrict__ emb, const float* __restrict__ attn_W,
    const float* __restrict__ attn_b, unsigned short* __restrict__ aXa,
    unsigned short* __restrict__ aH, float* __restrict__ attn_out,
    float* __restrict__ wbuf)
{
  __shared__ float sE[H_], sH[H_], sLog[64];
  int b = blockIdx.x;
  int t = threadIdx.x;
  const float* erow = emb + (size_t)input[b] * H_;
  const float* hrow = hidden + (size_t)b * H_;
  for (int i = t; i < H_; i += 256) { sE[i] = erow[i]; sH[i] = hrow[i]; }
  __syncthreads();
  int wv = t >> 6, lane = t & 63;
  for (int l = wv; l < L_; l += 4) {
    const float* wr = attn_W + (size_t)l * (2 * H_);
    float acc = 0.f;
    for (int m = lane; m < H_; m += 64)
      acc += sE[m] * wr[m] + sH[m] * wr[H_ + m];
    #pragma unroll
    for (int off = 32; off; off >>= 1) acc += __shfl_down(acc, off);
    if (lane == 0) sLog[l] = acc + attn_b[l];
  }
  __syncthreads();
  if (wv == 0) {
    float v = (lane < L_) ? sLog[lane] : -1e30f;
    float m = v;
    #pragma unroll
    for (int off = 32; off; off >>= 1) m = fmaxf(m, __shfl_xor(m, off));
    float e = (lane < L_) ? __expf(v - m) : 0.f;
    float s = e;
    #pragma unroll
    for (int off = 32; off; off >>= 1) s += __shfl_xor(s, off);
    float w = e / s;
    if (lane < L_) { attn_out[b * L_ + lane] = w; wbuf[b * 64 + lane] = w; }
  }
  // pack embedded -> aXa[k<H], hidden -> aH
  for (int k = t; k < H_; k += 256) {
    aXa[packIdx(b, k)] = f2bf(sE[k]);
    aH[packIdx(b, k)]  = f2bf(sH[k]);
  }
}

// ------------- attn part 2: weighted sum over enc, pack into aXa[k>=H] -------------
__global__ __launch_bounds__(256) void k_app(
    const float* __restrict__ enc, const float* __restrict__ wbuf,
    unsigned short* __restrict__ aXa)
{
  __shared__ float sWt[64];
  int b = blockIdx.x, q = blockIdx.y, t = threadIdx.x;
  if (t < L_) sWt[t] = wbuf[b * 64 + t];
  __syncthreads();
  int col = q * 256 + t;
  const float* eb = enc + (size_t)b * L_ * H_ + col;
  float acc = 0.f;
  #pragma unroll 4
  for (int l = 0; l < L_; ++l) acc += sWt[l] * eb[(size_t)l * H_];
  aXa[packIdx(b, H_ + col)] = f2bf(acc);
}

// ------------- MFMA GEMM: C[b,n] = sum_k A[b,k]*W[n,k] -------------
// Block: 32 cols x 128 rows; 4 waves, wave w -> rows 32w..32w+31 (bm pair), 2 col-tiles.
__global__ __launch_bounds__(256, 4) void k_gemm(
    const unsigned short* __restrict__ Apk, const float* __restrict__ Wt,
    const float* __restrict__ bias, float* __restrict__ Cdir,
    float* __restrict__ Cpart, int K, int N, int ldc, int steps)
{
  int t = threadIdx.x;
  int wv = t >> 6, lane = t & 63;
  int n0 = blockIdx.x * 32;
  int bm0 = wv * 2;
  int kgrp = (lane >> 4) * 8;
  int c0 = n0 + (lane & 15);
  int c1 = c0 + 16;
  int g0 = (c0 < N) ? c0 : (N - 1);
  int g1 = (c1 < N) ? c1 : (N - 1);
  int s0v = blockIdx.y * steps;
  const float* wp0 = Wt + (size_t)g0 * K + kgrp + (size_t)s0v * 32;
  const float* wp1 = Wt + (size_t)g1 * K + kgrp + (size_t)s0v * 32;
  const bf16x8* ap = (const bf16x8*)Apk + (size_t)(s0v * 8 + bm0) * 64 + lane;
  f32x4 acc00 = {0.f,0.f,0.f,0.f}, acc01 = acc00, acc10 = acc00, acc11 = acc00;
  for (int s = 0; s < steps; s += 2) {
    bf16x8 a00 = ap[0];          // step s,   bm0
    bf16x8 a01 = ap[64];         // step s,   bm0+1
    bf16x8 a10 = ap[512];        // step s+1, bm0
    bf16x8 a11 = ap[576];        // step s+1, bm0+1
    ap += 1024;
    float4 wA0 = *(const float4*)(wp0);
    float4 wA1 = *(const float4*)(wp0 + 4);
    float4 wB0 = *(const float4*)(wp0 + 32);
    float4 wB1 = *(const float4*)(wp0 + 36);
    wp0 += 64;
    float4 xA0 = *(const float4*)(wp1);
    float4 xA1 = *(const float4*)(wp1 + 4);
    float4 xB0 = *(const float4*)(wp1 + 32);
    float4 xB1 = *(const float4*)(wp1 + 36);
    wp1 += 64;
    bf16x8 f0 = cvt8(wA0, wA1);  // nc0 step s
    bf16x8 f1 = cvt8(wB0, wB1);  // nc0 step s+1
    bf16x8 h0 = cvt8(xA0, xA1);  // nc1 step s
    bf16x8 h1 = cvt8(xB0, xB1);  // nc1 step s+1
    acc00 = __builtin_amdgcn_mfma_f32_16x16x32_bf16(a00, f0, acc00, 0, 0, 0);
    acc10 = __builtin_amdgcn_mfma_f32_16x16x32_bf16(a01, f0, acc10, 0, 0, 0);
    acc01 = __builtin_amdgcn_mfma_f32_16x16x32_bf16(a00, h0, acc01, 0, 0, 0);
    acc11 = __builtin_amdgcn_mfma_f32_16x16x32_bf16(a01, h0, acc11, 0, 0, 0);
    acc00 = __builtin_amdgcn_mfma_f32_16x16x32_bf16(a10, f1, acc00, 0, 0, 0);
    acc10 = __builtin_amdgcn_mfma_f32_16x16x32_bf16(a11, f1, acc10, 0, 0, 0);
    acc01 = __builtin_amdgcn_mfma_f32_16x16x32_bf16(a10, h1, acc01, 0, 0, 0);
    acc11 = __builtin_amdgcn_mfma_f32_16x16x32_bf16(a11, h1, acc11, 0, 0, 0);
  }
  int rb = (lane >> 4) * 4;
  int row0 = bm0 * 16 + rb;
  int row1 = row0 + 16;
  if (Cpart) {
    float* dst = Cpart + (size_t)blockIdx.y * B_ * N;
    #pragma unroll
    for (int r = 0; r < 4; ++r) {
      if (c0 < N) { dst[(size_t)(row0 + r) * N + c0] = acc00[r];
                    dst[(size_t)(row1 + r) * N + c0] = acc10[r]; }
      if (c1 < N) { dst[(size_t)(row0 + r) * N + c1] = acc01[r];
                    dst[(size_t)(row1 + r) * N + c1] = acc11[r]; }
    }
  } else {
    float bv0 = (bias && c0 < N) ? bias[c0] : 0.f;
    float bv1 = (bias && c1 < N) ? bias[c1] : 0.f;
    #pragma unroll
    for (int r = 0; r < 4; ++r) {
      if (c0 < N) { Cdir[(size_t)(row0 + r) * ldc + c0] = acc00[r] + bv0;
                    Cdir[(size_t)(row1 + r) * ldc + c0] = acc10[r] + bv0; }
      if (c1 < N) { Cdir[(size_t)(row0 + r) * ldc + c1] = acc01[r] + bv1;
                    Cdir[(size_t)(row1 + r) * ldc + c1] = acc11[r] + bv1; }
    }
  }
}

// ------------- reduce combine partials + bias + relu -> packed x -------------
__global__ __launch_bounds__(256) void k_reduce_comb(
    const float* __restrict__ parts, const float* __restrict__ bias,
    unsigned short* __restrict__ aX)
{
  int idx = blockIdx.x * 256 + threadIdx.x;  // B_*H_
  int b = idx >> 10, j = idx & (H_ - 1);
  float s = bias[j];
  #pragma unroll
  for (int p = 0; p < 8; ++p) s += parts[(size_t)p * B_ * H_ + idx];
  s = fmaxf(s, 0.f);
  aX[packIdx(b, j)] = f2bf(s);
}

// ------------- GRU gates from split partials -> h_new (+packed) -------------
__global__ __launch_bounds__(256) void k_gate(
    const float* __restrict__ giP, const float* __restrict__ ghP,
    const float* __restrict__ b_ih, const float* __restrict__ b_hh,
    const float* __restrict__ hidden, float* __restrict__ hnew,
    unsigned short* __restrict__ aHn)
{
  int idx = blockIdx.x * 256 + threadIdx.x;  // B_*H_
  int b = idx >> 10, j = idx & (H_ - 1);
  size_t base = (size_t)b * 3 * H_;
  float ir = b_ih[j], iz = b_ih[H_ + j], in_ = b_ih[2 * H_ + j];
  float hr = b_hh[j], hz = b_hh[H_ + j], hn = b_hh[2 * H_ + j];
  #pragma unroll
  for (int p = 0; p < 4; ++p) {
    const float* gi = giP + (size_t)p * B_ * 3 * H_ + base;
    const float* gh = ghP + (size_t)p * B_ * 3 * H_ + base;
    ir += gi[j]; iz += gi[H_ + j]; in_ += gi[2 * H_ + j];
    hr += gh[j]; hz += gh[H_ + j]; hn += gh[2 * H_ + j];
  }
  float r = 1.f / (1.f + __expf(-(ir + hr)));
  float z = 1.f / (1.f + __expf(-(iz + hz)));
  float n = tanhf(in_ + r * hn);
  float h = hidden[idx];
  float hv = (1.f - z) * n + z * h;
  hnew[idx] = hv;
  aHn[packIdx(b, j)] = f2bf(hv);
}

// ------------- log_softmax phase 1: per-slice max & expsum -------------
#define SL_ 6283
__global__ __launch_bounds__(256) void k_lsm1(
    const float* __restrict__ logits, float* __restrict__ ms)
{
  __shared__ float red[4], red2[4];
  int b = blockIdx.x, sl = blockIdx.y, t = threadIdx.x;
  int v0 = sl * SL_;
  int v1 = v0 + SL_; if (v1 > V_) v1 = V_;
  const float* row = logits + (size_t)b * V_;
  float m = -1e30f;
  for (int v = v0 + t; v < v1; v += 256) m = fmaxf(m, row[v]);
  #pragma unroll
  for (int off = 32; off; off >>= 1) m = fmaxf(m, __shfl_xor(m, off));
  if ((t & 63) == 0) red[t >> 6] = m;
  __syncthreads();
  m = fmaxf(fmaxf(red[0], red[1]), fmaxf(red[2], red[3]));
  float s = 0.f;
  for (int v = v0 + t; v < v1; v += 256) s += __expf(row[v] - m);
  #pragma unroll
  for (int off = 32; off; off >>= 1) s += __shfl_xor(s, off);
  if ((t & 63) == 0) red2[t >> 6] = s;
  __syncthreads();
  if (t == 0) {
    s = red2[0] + red2[1] + red2[2] + red2[3];
    ms[(b * 8 + sl) * 2]     = m;
    ms[(b * 8 + sl) * 2 + 1] = s;
  }
}

// ------------- log_softmax phase 2: combine partials, subtract -------------
__global__ __launch_bounds__(256) void k_lsm2(
    float* __restrict__ logits, const float* __restrict__ ms)
{
  int b = blockIdx.x, sl = blockIdx.y, t = threadIdx.x;
  float M = -1e30f;
  #pragma unroll
  for (int i = 0; i < 8; ++i) M = fmaxf(M, ms[(b * 8 + i) * 2]);
  float S = 0.f;
  #pragma unroll
  for (int i = 0; i < 8; ++i)
    S += ms[(b * 8 + i) * 2 + 1] * __expf(ms[(b * 8 + i) * 2] - M);
  float c = M + logf(S);
  int v0 = sl * SL_;
  int v1 = v0 + SL_; if (v1 > V_) v1 = V_;
  float* row = logits + (size_t)b * V_;
  for (int v = v0 + t; v < v1; v += 256) row[v] -= c;
}

extern "C" void kernel_launch(void* const* d_in, const int* in_sizes, int n_in,
                              void* d_out, int out_size, void* d_ws, size_t ws_size,
                              hipStream_t stream)
{
  const int*   input  = (const int*)d_in[0];
  const float* hidden = (const float*)d_in[1];
  const float* enc    = (const float*)d_in[2];
  const float* emb    = (const float*)d_in[3];
  const float* attn_W = (const float*)d_in[4];
  const float* attn_b = (const float*)d_in[5];
  const float* comb_W = (const float*)d_in[6];
  const float* comb_b = (const float*)d_in[7];
  const float* W_ih   = (const float*)d_in[8];
  const float* W_hh   = (const float*)d_in[9];
  const float* b_ih   = (const float*)d_in[10];
  const float* b_hh   = (const float*)d_in[11];
  const float* out_W  = (const float*)d_in[12];
  const float* out_b  = (const float*)d_in[13];

  float* out    = (float*)d_out;
  float* logits = out;                        // [B,V]
  float* hnew   = out + (size_t)B_ * V_;      // [1,B,H]
  float* attnw  = hnew + (size_t)B_ * H_;     // [B,L]

  char* ws = (char*)d_ws;
  unsigned short* aXa = (unsigned short*)(ws);                    // 512 KB (K=2048)
  unsigned short* aH  = (unsigned short*)(ws + (512 << 10));      // 256 KB
  unsigned short* aX  = (unsigned short*)(ws + (768 << 10));      // 256 KB
  unsigned short* aHn = (unsigned short*)(ws + (1024 << 10));     // 256 KB
  float* wbuf  = (float*)(ws + (1280 << 10));                     // 32 KB
  float* msbuf = (float*)(ws + (1312 << 10));                     // 8 KB
  float* combP = (float*)(ws + (1344 << 10));                     // 8 * 512 KB
  float* giP   = (float*)(ws + (1344 << 10) + (4 << 20));         // 4 * 1.5 MB
  float* ghP   = (float*)(ws + (1344 << 10) + (10 << 20));        // 4 * 1.5 MB

  // 1. attention logits + softmax; pack embedded (aXa lo) + h (aH)
  k_attn1<<<B_, 256, 0, stream>>>(input, hidden, emb, attn_W, attn_b, aXa, aH, attnw, wbuf);
  // 2. attention weighted sum; pack into aXa hi
  k_app<<<dim3(B_, 4), 256, 0, stream>>>(enc, wbuf, aXa);
  // 3. combine GEMM (split-K 8)
  k_gemm<<<dim3(H_ / 32, 8), 256, 0, stream>>>(aXa, comb_W, nullptr, nullptr, combP,
                                               2 * H_, H_, H_, 8);
  // 4. reduce + bias + relu -> packed x
  k_reduce_comb<<<(B_ * H_) / 256, 256, 0, stream>>>(combP, comb_b, aX);
  // 5. gi = x @ W_ih^T, gh = h @ W_hh^T (split-K 4)
  k_gemm<<<dim3(3 * H_ / 32, 4), 256, 0, stream>>>(aX, W_ih, nullptr, nullptr, giP,
                                                   H_, 3 * H_, 3 * H_, 8);
  k_gemm<<<dim3(3 * H_ / 32, 4), 256, 0, stream>>>(aH, W_hh, nullptr, nullptr, ghP,
                                                   H_, 3 * H_, 3 * H_, 8);
  // 6. gates -> h_new (out) + packed h_new
  k_gate<<<(B_ * H_) / 256, 256, 0, stream>>>(giP, ghP, b_ih, b_hh, hidden, hnew, aHn);
  // 7. projection: logits = h_new @ out_W^T + out_b (direct to d_out)
  k_gemm<<<dim3((V_ + 31) / 32, 1), 256, 0, stream>>>(aHn, out_W, out_b, logits, nullptr,
                                                      H_, V_, V_, 32);
  // 8-9. two-phase log_softmax
  k_lsm1<<<dim3(B_, 8), 256, 0, stream>>>(logits, msbuf);
  k_lsm2<<<dim3(B_, 8), 256, 0, stream>>>(logits, msbuf);
}

// Round 3
// 209.032 us; speedup vs baseline: 1.5833x; 1.3916x over previous
//
#include <hip/hip_runtime.h>
#include <hip/hip_bf16.h>

#define B_ 128
#define H_ 1024
#define L_ 60
#define V_ 50257
#define BK 64

typedef __attribute__((ext_vector_type(8))) short bf16x8;
typedef __attribute__((ext_vector_type(4))) float f32x4;

__device__ __forceinline__ unsigned short f2bf(float f) {
  union { __hip_bfloat16 h; unsigned short u; } v;
  v.h = __float2bfloat16(f);
  return v.u;
}

__device__ __forceinline__ bf16x8 cvt8(float4 a, float4 b) {
  union { bf16x8 v; __hip_bfloat16 h[8]; } u;
  u.h[0] = __float2bfloat16(a.x); u.h[1] = __float2bfloat16(a.y);
  u.h[2] = __float2bfloat16(a.z); u.h[3] = __float2bfloat16(a.w);
  u.h[4] = __float2bfloat16(b.x); u.h[5] = __float2bfloat16(b.y);
  u.h[6] = __float2bfloat16(b.z); u.h[7] = __float2bfloat16(b.w);
  return u.v;
}

__device__ __forceinline__ void gl_lds16(const float* g, float* l) {
  __builtin_amdgcn_global_load_lds(
      (const __attribute__((address_space(1))) unsigned int*)g,
      (__attribute__((address_space(3))) unsigned int*)l, 16, 0, 0);
}

// bf16 A-fragment pack position for MFMA 16x16x32 (verified R1/R2):
// fragment ((s*8+bm)*64+lane), elem j ; lane holds A[row=l&15][k=(l>>4)*8+j]
__device__ __forceinline__ size_t packIdx(int b, int k) {
  int s = k >> 5;
  int bm = b >> 4;
  int lane = (b & 15) | (((k >> 3) & 3) << 4);
  return ((size_t)((s * 8 + bm) * 64 + lane) << 3) | (size_t)(k & 7);
}

// ------------- attn part 1: embed gather, logits, softmax; pack embedded + h -------------
__global__ __launch_bounds__(256) void k_attn1(
    const int* __restrict__ input, const float* __restrict__ hidden,
    const float* __restrict__ emb, const float* __restrict__ attn_W,
    const float* __restrict__ attn_b, unsigned short* __restrict__ aXa,
    unsigned short* __restrict__ aH, float* __restrict__ attn_out,
    float* __restrict__ wbuf)
{
  __shared__ float sE[H_], sH[H_], sLog[64];
  int b = blockIdx.x;
  int t = threadIdx.x;
  const float* erow = emb + (size_t)input[b] * H_;
  const float* hrow = hidden + (size_t)b * H_;
  for (int i = t; i < H_; i += 256) { sE[i] = erow[i]; sH[i] = hrow[i]; }
  __syncthreads();
  int wv = t >> 6, lane = t & 63;
  for (int l = wv; l < L_; l += 4) {
    const float* wr = attn_W + (size_t)l * (2 * H_);
    float acc = 0.f;
    for (int m = lane; m < H_; m += 64)
      acc += sE[m] * wr[m] + sH[m] * wr[H_ + m];
    #pragma unroll
    for (int off = 32; off; off >>= 1) acc += __shfl_down(acc, off);
    if (lane == 0) sLog[l] = acc + attn_b[l];
  }
  __syncthreads();
  if (wv == 0) {
    float v = (lane < L_) ? sLog[lane] : -1e30f;
    float m = v;
    #pragma unroll
    for (int off = 32; off; off >>= 1) m = fmaxf(m, __shfl_xor(m, off));
    float e = (lane < L_) ? __expf(v - m) : 0.f;
    float s = e;
    #pragma unroll
    for (int off = 32; off; off >>= 1) s += __shfl_xor(s, off);
    float w = e / s;
    if (lane < L_) { attn_out[b * L_ + lane] = w; wbuf[b * 64 + lane] = w; }
  }
  for (int k = t; k < H_; k += 256) {
    aXa[packIdx(b, k)] = f2bf(sE[k]);
    aH[packIdx(b, k)]  = f2bf(sH[k]);
  }
}

// ------------- attn part 2: weighted sum over enc, pack into aXa[k>=H] -------------
__global__ __launch_bounds__(256) void k_app(
    const float* __restrict__ enc, const float* __restrict__ wbuf,
    unsigned short* __restrict__ aXa)
{
  __shared__ float sWt[64];
  int b = blockIdx.x, q = blockIdx.y, t = threadIdx.x;
  if (t < L_) sWt[t] = wbuf[b * 64 + t];
  __syncthreads();
  int col = q * 256 + t;
  const float* eb = enc + (size_t)b * L_ * H_ + col;
  float acc = 0.f;
  #pragma unroll 4
  for (int l = 0; l < L_; ++l) acc += sWt[l] * eb[(size_t)l * H_];
  aXa[packIdx(b, H_ + col)] = f2bf(acc);
}

// ------------- LDS-staged MFMA GEMM: C[b,n] = sum_k A[b,k]*W[n,k] -------------
// Tile 128(B) x 64(N), BK=64 f32 chunks double-buffered via global_load_lds (16B,
// coalesced 1KB/instr). XOR swizzle (chunk ^ (row&7)) applied on global SOURCE
// (LDS dest stays linear) and on LDS reads -> 2-way-free ds_read_b128.
// Wave w: rows [32w,32w+32) (bm pair) x all 4 nc tiles. Split-K via blockIdx.y.
// halfY>0: dispatch fused pair (y>=halfY uses Apk2/Wt2/Cpart2).
// pms!=null: also emit per-(row, block) softmax partials (max, expsum).
__global__ __launch_bounds__(256) void k_gemm(
    const unsigned short* __restrict__ Apk, const unsigned short* __restrict__ Apk2,
    const float* __restrict__ Wt, const float* __restrict__ Wt2,
    const float* __restrict__ bias, float* __restrict__ Cdir,
    float* __restrict__ Cpart, float* __restrict__ Cpart2,
    float* __restrict__ pms, int K, int N, int nchunks, int halfY, int nblkx)
{
  __shared__ __align__(16) float buf[2][64 * BK];
  int t = threadIdx.x, wv = t >> 6, lane = t & 63;
  int y = blockIdx.y;
  const unsigned short* A = Apk;
  const float* W = Wt;
  float* CP = Cpart;
  int sidx = y;
  if (halfY && y >= halfY) { A = Apk2; W = Wt2; CP = Cpart2; sidx = y - halfY; }
  int chunk0 = sidx * nchunks;
  int n0 = blockIdx.x * 64;
  int srow = lane >> 4;        // staging: row within 4-row group
  int schunk = lane & 15;      // staging: 16B chunk within 256B row

  f32x4 acc[2][4];
  #pragma unroll
  for (int i = 0; i < 2; ++i)
    #pragma unroll
    for (int j = 0; j < 4; ++j) acc[i][j] = (f32x4){0.f, 0.f, 0.f, 0.f};

  auto STAGE = [&](int kc, int bi) {
    #pragma unroll
    for (int i = 0; i < 4; ++i) {
      int rbase = wv * 16 + i * 4;
      int r = rbase + srow;
      int gcol = n0 + r; gcol = (gcol < N) ? gcol : (N - 1);
      int g = schunk ^ (r & 7);
      const float* src = W + (size_t)gcol * K + (size_t)kc * BK + g * 4;
      gl_lds16(src, &buf[bi][rbase * BK]);
    }
  };

  STAGE(chunk0, 0);
  __syncthreads();

  int bm0 = wv * 2;
  const bf16x8* apg = (const bf16x8*)A;
  for (int kk = 0; kk < nchunks; ++kk) {
    if (kk + 1 < nchunks) STAGE(chunk0 + kk + 1, (kk + 1) & 1);
    const float* bp = buf[kk & 1];
    int sb = (chunk0 + kk) * 2;
    #pragma unroll
    for (int ks = 0; ks < 2; ++ks) {
      int s = sb + ks;
      bf16x8 a0 = apg[((size_t)s * 8 + bm0) * 64 + lane];
      bf16x8 a1 = apg[((size_t)s * 8 + bm0 + 1) * 64 + lane];
      #pragma unroll
      for (int nc = 0; nc < 4; ++nc) {
        int rr = nc * 16 + (lane & 15);
        int gg = ks * 8 + (lane >> 4) * 2;
        int c0 = gg ^ (lane & 7), c1 = (gg + 1) ^ (lane & 7);
        float4 w0 = *(const float4*)&bp[rr * BK + c0 * 4];
        float4 w1 = *(const float4*)&bp[rr * BK + c1 * 4];
        bf16x8 bfr = cvt8(w0, w1);
        acc[0][nc] = __builtin_amdgcn_mfma_f32_16x16x32_bf16(a0, bfr, acc[0][nc], 0, 0, 0);
        acc[1][nc] = __builtin_amdgcn_mfma_f32_16x16x32_bf16(a1, bfr, acc[1][nc], 0, 0, 0);
      }
    }
    __syncthreads();
  }

  int cols[4]; float bv[4];
  #pragma unroll
  for (int nc = 0; nc < 4; ++nc) {
    int c = n0 + nc * 16 + (lane & 15);
    cols[nc] = c;
    bv[nc] = (bias && c < N) ? bias[c] : 0.f;
  }
  int rb = (lane >> 4) * 4;
  if (CP) {
    float* dst = CP + (size_t)sidx * B_ * N;
    #pragma unroll
    for (int bm = 0; bm < 2; ++bm)
      #pragma unroll
      for (int r = 0; r < 4; ++r) {
        int row = (bm0 + bm) * 16 + rb + r;
        #pragma unroll
        for (int nc = 0; nc < 4; ++nc)
          if (cols[nc] < N) dst[(size_t)row * N + cols[nc]] = acc[bm][nc][r];
      }
  } else {
    #pragma unroll
    for (int bm = 0; bm < 2; ++bm)
      #pragma unroll
      for (int r = 0; r < 4; ++r) {
        int row = (bm0 + bm) * 16 + rb + r;
        #pragma unroll
        for (int nc = 0; nc < 4; ++nc)
          if (cols[nc] < N) Cdir[(size_t)row * N + cols[nc]] = acc[bm][nc][r] + bv[nc];
      }
    if (pms) {
      #pragma unroll
      for (int bm = 0; bm < 2; ++bm)
        #pragma unroll
        for (int r = 0; r < 4; ++r) {
          int row = (bm0 + bm) * 16 + rb + r;
          float m = -1e30f;
          #pragma unroll
          for (int nc = 0; nc < 4; ++nc)
            if (cols[nc] < N) m = fmaxf(m, acc[bm][nc][r] + bv[nc]);
          #pragma unroll
          for (int off = 8; off; off >>= 1) m = fmaxf(m, __shfl_xor(m, off));
          float e = 0.f;
          #pragma unroll
          for (int nc = 0; nc < 4; ++nc)
            if (cols[nc] < N) e += __expf(acc[bm][nc][r] + bv[nc] - m);
          #pragma unroll
          for (int off = 8; off; off >>= 1) e += __shfl_xor(e, off);
          if ((lane & 15) == 0) {
            size_t o = ((size_t)row * nblkx + blockIdx.x) * 2;
            pms[o] = m; pms[o + 1] = e;
          }
        }
    }
  }
}

// ------------- reduce combine partials + bias + relu -> packed x -------------
__global__ __launch_bounds__(256) void k_reduce_comb(
    const float* __restrict__ parts, const float* __restrict__ bias,
    unsigned short* __restrict__ aX)
{
  int idx = blockIdx.x * 256 + threadIdx.x;  // B_*H_
  int b = idx >> 10, j = idx & (H_ - 1);
  float s = bias[j];
  #pragma unroll
  for (int p = 0; p < 8; ++p) s += parts[(size_t)p * B_ * H_ + idx];
  s = fmaxf(s, 0.f);
  aX[packIdx(b, j)] = f2bf(s);
}

// ------------- GRU gates from split partials -> h_new (+packed) -------------
__global__ __launch_bounds__(256) void k_gate(
    const float* __restrict__ giP, const float* __restrict__ ghP,
    const float* __restrict__ b_ih, const float* __restrict__ b_hh,
    const float* __restrict__ hidden, float* __restrict__ hnew,
    unsigned short* __restrict__ aHn)
{
  int idx = blockIdx.x * 256 + threadIdx.x;  // B_*H_
  int b = idx >> 10, j = idx & (H_ - 1);
  size_t base = (size_t)b * 3 * H_;
  float ir = b_ih[j], iz = b_ih[H_ + j], in_ = b_ih[2 * H_ + j];
  float hr = b_hh[j], hz = b_hh[H_ + j], hn = b_hh[2 * H_ + j];
  #pragma unroll
  for (int p = 0; p < 4; ++p) {
    const float* gi = giP + (size_t)p * B_ * 3 * H_ + base;
    const float* gh = ghP + (size_t)p * B_ * 3 * H_ + base;
    ir += gi[j]; iz += gi[H_ + j]; in_ += gi[2 * H_ + j];
    hr += gh[j]; hz += gh[H_ + j]; hn += gh[2 * H_ + j];
  }
  float r = 1.f / (1.f + __expf(-(ir + hr)));
  float z = 1.f / (1.f + __expf(-(iz + hz)));
  float n = tanhf(in_ + r * hn);
  float h = hidden[idx];
  float hv = (1.f - z) * n + z * h;
  hnew[idx] = hv;
  aHn[packIdx(b, j)] = f2bf(hv);
}

// ------------- log_softmax: reduce per-block partials -> per-row constant -------------
__global__ __launch_bounds__(256) void k_lsmr(
    const float* __restrict__ pms, float* __restrict__ cbuf, int nblk)
{
  __shared__ float sm[4], ss[4];
  int b = blockIdx.x, t = threadIdx.x;
  float M = -1e30f, S = 0.f;
  for (int i = t; i < nblk; i += 256) {
    float m = pms[((size_t)b * nblk + i) * 2];
    float s = pms[((size_t)b * nblk + i) * 2 + 1];
    float nm = fmaxf(M, m);
    S = S * __expf(M - nm) + s * __expf(m - nm);
    M = nm;
  }
  #pragma unroll
  for (int off = 32; off; off >>= 1) {
    float m2 = __shfl_xor(M, off), s2 = __shfl_xor(S, off);
    float nm = fmaxf(M, m2);
    S = S * __expf(M - nm) + s2 * __expf(m2 - nm);
    M = nm;
  }
  if ((t & 63) == 0) { sm[t >> 6] = M; ss[t >> 6] = S; }
  __syncthreads();
  if (t == 0) {
    float Mf = M, Sf = S;
    #pragma unroll
    for (int i = 1; i < 4; ++i) {
      float nm = fmaxf(Mf, sm[i]);
      Sf = Sf * __expf(Mf - nm) + ss[i] * __expf(sm[i] - nm);
      Mf = nm;
    }
    cbuf[b] = Mf + logf(Sf);
  }
}

// ------------- log_softmax subtract -------------
#define SL_ 6283
__global__ __launch_bounds__(256) void k_lsub(
    float* __restrict__ logits, const float* __restrict__ cbuf)
{
  int b = blockIdx.x, sl = blockIdx.y, t = threadIdx.x;
  float c = cbuf[b];
  int v0 = sl * SL_;
  int v1 = v0 + SL_; if (v1 > V_) v1 = V_;
  float* row = logits + (size_t)b * V_;
  for (int v = v0 + t; v < v1; v += 256) row[v] -= c;
}

extern "C" void kernel_launch(void* const* d_in, const int* in_sizes, int n_in,
                              void* d_out, int out_size, void* d_ws, size_t ws_size,
                              hipStream_t stream)
{
  const int*   input  = (const int*)d_in[0];
  const float* hidden = (const float*)d_in[1];
  const float* enc    = (const float*)d_in[2];
  const float* emb    = (const float*)d_in[3];
  const float* attn_W = (const float*)d_in[4];
  const float* attn_b = (const float*)d_in[5];
  const float* comb_W = (const float*)d_in[6];
  const float* comb_b = (const float*)d_in[7];
  const float* W_ih   = (const float*)d_in[8];
  const float* W_hh   = (const float*)d_in[9];
  const float* b_ih   = (const float*)d_in[10];
  const float* b_hh   = (const float*)d_in[11];
  const float* out_W  = (const float*)d_in[12];
  const float* out_b  = (const float*)d_in[13];

  float* out    = (float*)d_out;
  float* logits = out;                        // [B,V]
  float* hnew   = out + (size_t)B_ * V_;      // [1,B,H]
  float* attnw  = hnew + (size_t)B_ * H_;     // [B,L]

  const int NBLK = (V_ + 63) / 64;            // 786
  char* ws = (char*)d_ws;
  unsigned short* aXa = (unsigned short*)(ws);                 // 512K
  unsigned short* aH  = (unsigned short*)(ws + 524288);        // 256K
  unsigned short* aX  = (unsigned short*)(ws + 786432);        // 256K
  unsigned short* aHn = (unsigned short*)(ws + 1048576);       // 256K
  float* wbuf  = (float*)(ws + 1310720);                       // 32K
  float* cbuf  = (float*)(ws + 1343488);                       // 4K
  float* pms   = (float*)(ws + 1347584);                       // 786K (786*128*8B)
  float* combP = (float*)(ws + 2155520);                       // 4MB  (8 splits)
  float* giP   = (float*)(ws + 6349824);                       // 6MB  (4 splits)
  float* ghP   = (float*)(ws + 12641280);                      // 6MB  (4 splits)

  // 1. attention logits + softmax; pack embedded (aXa lo) + h (aH)
  k_attn1<<<B_, 256, 0, stream>>>(input, hidden, emb, attn_W, attn_b, aXa, aH, attnw, wbuf);
  // 2. attention weighted sum; pack into aXa hi
  k_app<<<dim3(B_, 4), 256, 0, stream>>>(enc, wbuf, aXa);
  // 3. combine GEMM: K=2048 (32 chunks), 8 splits x 4 chunks
  k_gemm<<<dim3(16, 8), 256, 0, stream>>>(aXa, nullptr, comb_W, nullptr, nullptr,
                                          nullptr, combP, nullptr, nullptr,
                                          2 * H_, H_, 4, 0, 0);
  // 4. reduce + bias + relu -> packed x
  k_reduce_comb<<<(B_ * H_) / 256, 256, 0, stream>>>(combP, comb_b, aX);
  // 5. fused gi|gh GEMMs: K=1024 (16 chunks), each 4 splits x 4 chunks
  k_gemm<<<dim3(48, 8), 256, 0, stream>>>(aX, aH, W_ih, W_hh, nullptr,
                                          nullptr, giP, ghP, nullptr,
                                          H_, 3 * H_, 4, 4, 0);
  // 6. gates -> h_new (out) + packed h_new
  k_gate<<<(B_ * H_) / 256, 256, 0, stream>>>(giP, ghP, b_ih, b_hh, hidden, hnew, aHn);
  // 7. projection + bias + softmax partials (fused lsm pass 1)
  k_gemm<<<dim3(NBLK, 1), 256, 0, stream>>>(aHn, nullptr, out_W, nullptr, out_b,
                                            logits, nullptr, nullptr, pms,
                                            H_, V_, 16, 0, NBLK);
  // 8. combine softmax partials -> per-row constant
  k_lsmr<<<B_, 256, 0, stream>>>(pms, cbuf, NBLK);
  // 9. subtract
  k_lsub<<<dim3(B_, 8), 256, 0, stream>>>(logits, cbuf);
}

// Round 4
// 133.623 us; speedup vs baseline: 2.4768x; 1.5643x over previous
//
#include <hip/hip_runtime.h>
#include <hip/hip_bf16.h>

#define B_ 128
#define H_ 1024
#define L_ 60
#define V_ 50257

typedef __attribute__((ext_vector_type(8))) short bf16x8;
typedef __attribute__((ext_vector_type(4))) float f32x4;

__device__ __forceinline__ unsigned short f2bf(float f) {
  union { __hip_bfloat16 h; unsigned short u; } v;
  v.h = __float2bfloat16(f);
  return v.u;
}

__device__ __forceinline__ bf16x8 cvt8(float4 a, float4 b) {
  union { bf16x8 v; __hip_bfloat16 h[8]; } u;
  u.h[0] = __float2bfloat16(a.x); u.h[1] = __float2bfloat16(a.y);
  u.h[2] = __float2bfloat16(a.z); u.h[3] = __float2bfloat16(a.w);
  u.h[4] = __float2bfloat16(b.x); u.h[5] = __float2bfloat16(b.y);
  u.h[6] = __float2bfloat16(b.z); u.h[7] = __float2bfloat16(b.w);
  return u.v;
}

__device__ __forceinline__ void gl_lds16(const void* g, void* l) {
  __builtin_amdgcn_global_load_lds(
      (const __attribute__((address_space(1))) unsigned int*)g,
      (__attribute__((address_space(3))) unsigned int*)l, 16, 0, 0);
}

#define SBAR()   __builtin_amdgcn_s_barrier()
#define SCHED0() __builtin_amdgcn_sched_barrier(0)
__device__ __forceinline__ void vwait4() { asm volatile("s_waitcnt vmcnt(4)" ::: "memory"); }
__device__ __forceinline__ void vwait0() { asm volatile("s_waitcnt vmcnt(0)" ::: "memory"); }

// bf16 A-fragment pack position for MFMA 16x16x32 (verified R1-R3):
// fragment ((s*8+bm)*64+lane), elem j ; lane holds A[row=l&15][k=(l>>4)*8+j]
__device__ __forceinline__ size_t packIdx(int b, int k) {
  int s = k >> 5;
  int bm = b >> 4;
  int lane = (b & 15) | (((k >> 3) & 3) << 4);
  return ((size_t)((s * 8 + bm) * 64 + lane) << 3) | (size_t)(k & 7);
}

// ------------- pack embedded + hidden into fragment layout -------------
__global__ __launch_bounds__(256) void k_embh(
    const int* __restrict__ input, const float* __restrict__ hidden,
    const float* __restrict__ emb, unsigned short* __restrict__ aXa,
    unsigned short* __restrict__ aH)
{
  int idx = blockIdx.x * 256 + threadIdx.x;  // B_*H_
  int b = idx >> 10, j = idx & (H_ - 1);
  float e = emb[(size_t)input[b] * H_ + j];
  float h = hidden[idx];
  size_t p = packIdx(b, j);
  aXa[p] = f2bf(e);
  aH[p]  = f2bf(h);
}

// ------------- attention logits: one wave per (b,l) -------------
__global__ __launch_bounds__(256) void k_alog(
    const int* __restrict__ input, const float* __restrict__ hidden,
    const float* __restrict__ emb, const float* __restrict__ attn_W,
    const float* __restrict__ attn_b, float* __restrict__ lbuf)
{
  int t = threadIdx.x, wv = t >> 6, lane = t & 63;
  int task = blockIdx.x * 4 + wv;            // 0 .. B_*L_-1
  int b = task / L_, l = task - b * L_;
  const float* erow = emb + (size_t)input[b] * H_;
  const float* hrow = hidden + (size_t)b * H_;
  const float* wr = attn_W + (size_t)l * (2 * H_);
  float acc = 0.f;
  #pragma unroll 4
  for (int i = 0; i < 16; ++i) {
    int m = lane + i * 64;
    acc += erow[m] * wr[m] + hrow[m] * wr[H_ + m];
  }
  #pragma unroll
  for (int off = 32; off; off >>= 1) acc += __shfl_xor(acc, off);
  if (lane == 0) lbuf[b * 64 + l] = acc + attn_b[l];
}

// ------------- attention softmax: one wave per b -------------
__global__ __launch_bounds__(256) void k_asm(
    const float* __restrict__ lbuf, float* __restrict__ attnw,
    float* __restrict__ wbuf)
{
  int t = threadIdx.x, wv = t >> 6, lane = t & 63;
  int b = blockIdx.x * 4 + wv;
  float v = (lane < L_) ? lbuf[b * 64 + lane] : -1e30f;
  float m = v;
  #pragma unroll
  for (int off = 32; off; off >>= 1) m = fmaxf(m, __shfl_xor(m, off));
  float e = (lane < L_) ? __expf(v - m) : 0.f;
  float s = e;
  #pragma unroll
  for (int off = 32; off; off >>= 1) s += __shfl_xor(s, off);
  float w = e / s;
  if (lane < L_) { attnw[b * L_ + lane] = w; wbuf[b * 64 + lane] = w; }
}

// ------------- attention weighted sum over enc, pack into aXa[k>=H] -------------
__global__ __launch_bounds__(256) void k_app(
    const float* __restrict__ enc, const float* __restrict__ wbuf,
    unsigned short* __restrict__ aXa)
{
  __shared__ float sWt[64];
  int b = blockIdx.x, q = blockIdx.y, t = threadIdx.x;
  if (t < L_) sWt[t] = wbuf[b * 64 + t];
  __syncthreads();
  int col = q * 256 + t;
  const float* eb = enc + (size_t)b * L_ * H_ + col;
  float acc = 0.f;
  #pragma unroll 4
  for (int l = 0; l < L_; ++l) acc += sWt[l] * eb[(size_t)l * H_];
  aXa[packIdx(b, H_ + col)] = f2bf(acc);
}

// ------------- LDS-staged MFMA GEMM, counted-vmcnt pipeline -------------
// C[b,n] = sum_k A[b,k]*W[n,k]. Tile 128(B) x 64(N), BK=32.
// Per chunk: W 8KB (XOR-swizzled both sides) + A 8KB (linear), both staged via
// global_load_lds. 2-deep prefetch; s_waitcnt vmcnt(4) (never 0 mid-loop) +
// raw s_barrier -> prefetch loads stay in flight across barriers (T3+T4).
// Wave w: rows [32w,32w+32) x 4 nc col-tiles. Split-K via blockIdx.y.
// halfY>0: fused pair (y>=halfY uses Apk2/Wt2/Cpart2).
// pms!=null: emit per-(row, blockx) softmax partials (max, expsum).
__global__ __launch_bounds__(256) void k_gemm(
    const unsigned short* __restrict__ Apk, const unsigned short* __restrict__ Apk2,
    const float* __restrict__ Wt, const float* __restrict__ Wt2,
    const float* __restrict__ bias, float* __restrict__ Cdir,
    float* __restrict__ Cpart, float* __restrict__ Cpart2,
    float* __restrict__ pms, int K, int N, int nchunks, int halfY, int nblkx)
{
  __shared__ __align__(16) float bufW[2][64 * 32];            // 2 x 8KB
  __shared__ __align__(16) unsigned short bufA[2][128 * 32];  // 2 x 8KB
  int t = threadIdx.x, wv = t >> 6, lane = t & 63;
  int y = blockIdx.y;
  const unsigned short* A = Apk;
  const float* W = Wt;
  float* CP = Cpart;
  int sidx = y;
  if (halfY && y >= halfY) { A = Apk2; W = Wt2; CP = Cpart2; sidx = y - halfY; }
  int chunk0 = sidx * nchunks;
  int n0 = blockIdx.x * 64;
  int bm0 = wv * 2;
  int srow8 = lane >> 3;     // row within 8-row staging group
  int sch = lane & 7;        // 16B chunk within 128B row

  f32x4 acc[2][4];
  #pragma unroll
  for (int i = 0; i < 2; ++i)
    #pragma unroll
    for (int j = 0; j < 4; ++j) acc[i][j] = (f32x4){0.f, 0.f, 0.f, 0.f};

  auto STAGE = [&](int kc, int bi) {
    // W: wave wv rows [16wv,16wv+16), 2 calls x 8 rows x 128B, swizzled source
    #pragma unroll
    for (int i = 0; i < 2; ++i) {
      int r = wv * 16 + i * 8 + srow8;
      int gcol = n0 + r; gcol = (gcol < N) ? gcol : (N - 1);
      int c = sch ^ (r & 7);
      const float* src = W + (size_t)gcol * K + (size_t)kc * 32 + c * 4;
      gl_lds16(src, &bufW[bi][(wv * 16 + i * 8) * 32]);
    }
    // A: wave wv fragments bm0..bm0+1, 1KB each, linear copy
    #pragma unroll
    for (int j = 0; j < 2; ++j) {
      const unsigned short* src = A + ((size_t)kc * 8 + bm0 + j) * 512 + lane * 8;
      gl_lds16(src, &bufA[bi][(bm0 + j) * 512]);
    }
  };

  STAGE(chunk0, 0);
  STAGE(chunk0 + 1, 1);
  vwait4(); SCHED0(); SBAR();

  int g = lane >> 4;
  for (int kk = 0; kk < nchunks; ++kk) {
    const float* bw = bufW[kk & 1];
    const unsigned short* ba = bufA[kk & 1];
    bf16x8 a0 = *(const bf16x8*)&ba[(bm0) * 512 + lane * 8];
    bf16x8 a1 = *(const bf16x8*)&ba[(bm0 + 1) * 512 + lane * 8];
    #pragma unroll
    for (int nc = 0; nc < 4; ++nc) {
      int rr = nc * 16 + (lane & 15);
      int c0 = (g * 2) ^ (rr & 7);
      int c1 = (g * 2 + 1) ^ (rr & 7);
      float4 w0 = *(const float4*)&bw[rr * 32 + c0 * 4];
      float4 w1 = *(const float4*)&bw[rr * 32 + c1 * 4];
      bf16x8 bfr = cvt8(w0, w1);
      acc[0][nc] = __builtin_amdgcn_mfma_f32_16x16x32_bf16(a0, bfr, acc[0][nc], 0, 0, 0);
      acc[1][nc] = __builtin_amdgcn_mfma_f32_16x16x32_bf16(a1, bfr, acc[1][nc], 0, 0, 0);
    }
    if (kk + 1 < nchunks) {
      SCHED0(); SBAR();              // all waves done reading buf[kk&1]
      if (kk + 2 < nchunks) { STAGE(chunk0 + kk + 2, kk & 1); vwait4(); }
      else                  { vwait0(); }
      SCHED0(); SBAR();              // buf[(kk+1)&1] landed for all waves
    }
  }

  int cols[4]; float bv[4];
  #pragma unroll
  for (int nc = 0; nc < 4; ++nc) {
    int c = n0 + nc * 16 + (lane & 15);
    cols[nc] = c;
    bv[nc] = (bias && c < N) ? bias[c] : 0.f;
  }
  int rb = (lane >> 4) * 4;
  if (CP) {
    float* dst = CP + (size_t)sidx * B_ * N;
    #pragma unroll
    for (int bm = 0; bm < 2; ++bm)
      #pragma unroll
      for (int r = 0; r < 4; ++r) {
        int row = (bm0 + bm) * 16 + rb + r;
        #pragma unroll
        for (int nc = 0; nc < 4; ++nc)
          if (cols[nc] < N) dst[(size_t)row * N + cols[nc]] = acc[bm][nc][r];
      }
  } else {
    #pragma unroll
    for (int bm = 0; bm < 2; ++bm)
      #pragma unroll
      for (int r = 0; r < 4; ++r) {
        int row = (bm0 + bm) * 16 + rb + r;
        #pragma unroll
        for (int nc = 0; nc < 4; ++nc)
          if (cols[nc] < N) Cdir[(size_t)row * N + cols[nc]] = acc[bm][nc][r] + bv[nc];
      }
    if (pms) {
      #pragma unroll
      for (int bm = 0; bm < 2; ++bm)
        #pragma unroll
        for (int r = 0; r < 4; ++r) {
          int row = (bm0 + bm) * 16 + rb + r;
          float m = -1e30f;
          #pragma unroll
          for (int nc = 0; nc < 4; ++nc)
            if (cols[nc] < N) m = fmaxf(m, acc[bm][nc][r] + bv[nc]);
          #pragma unroll
          for (int off = 8; off; off >>= 1) m = fmaxf(m, __shfl_xor(m, off));
          float e = 0.f;
          #pragma unroll
          for (int nc = 0; nc < 4; ++nc)
            if (cols[nc] < N) e += __expf(acc[bm][nc][r] + bv[nc] - m);
          #pragma unroll
          for (int off = 8; off; off >>= 1) e += __shfl_xor(e, off);
          if ((lane & 15) == 0) {
            size_t o = ((size_t)row * nblkx + blockIdx.x) * 2;
            pms[o] = m; pms[o + 1] = e;
          }
        }
    }
  }
}

// ------------- reduce combine partials + bias + relu -> packed x -------------
__global__ __launch_bounds__(256) void k_reduce_comb(
    const float* __restrict__ parts, const float* __restrict__ bias,
    unsigned short* __restrict__ aX)
{
  int idx = blockIdx.x * 256 + threadIdx.x;  // B_*H_
  int b = idx >> 10, j = idx & (H_ - 1);
  float s = bias[j];
  #pragma unroll
  for (int p = 0; p < 8; ++p) s += parts[(size_t)p * B_ * H_ + idx];
  s = fmaxf(s, 0.f);
  aX[packIdx(b, j)] = f2bf(s);
}

// ------------- GRU gates from split partials -> h_new (+packed) -------------
__global__ __launch_bounds__(256) void k_gate(
    const float* __restrict__ giP, const float* __restrict__ ghP,
    const float* __restrict__ b_ih, const float* __restrict__ b_hh,
    const float* __restrict__ hidden, float* __restrict__ hnew,
    unsigned short* __restrict__ aHn)
{
  int idx = blockIdx.x * 256 + threadIdx.x;  // B_*H_
  int b = idx >> 10, j = idx & (H_ - 1);
  size_t base = (size_t)b * 3 * H_;
  float ir = b_ih[j], iz = b_ih[H_ + j], in_ = b_ih[2 * H_ + j];
  float hr = b_hh[j], hz = b_hh[H_ + j], hn = b_hh[2 * H_ + j];
  #pragma unroll
  for (int p = 0; p < 4; ++p) {
    const float* gi = giP + (size_t)p * B_ * 3 * H_ + base;
    const float* gh = ghP + (size_t)p * B_ * 3 * H_ + base;
    ir += gi[j]; iz += gi[H_ + j]; in_ += gi[2 * H_ + j];
    hr += gh[j]; hz += gh[H_ + j]; hn += gh[2 * H_ + j];
  }
  float r = 1.f / (1.f + __expf(-(ir + hr)));
  float z = 1.f / (1.f + __expf(-(iz + hz)));
  float n = tanhf(in_ + r * hn);
  float h = hidden[idx];
  float hv = (1.f - z) * n + z * h;
  hnew[idx] = hv;
  aHn[packIdx(b, j)] = f2bf(hv);
}

// ------------- log_softmax: reduce per-block partials -> per-row constant -------------
__global__ __launch_bounds__(256) void k_lsmr(
    const float* __restrict__ pms, float* __restrict__ cbuf, int nblk)
{
  __shared__ float sm[4], ss[4];
  int b = blockIdx.x, t = threadIdx.x;
  float M = -1e30f, S = 0.f;
  for (int i = t; i < nblk; i += 256) {
    float m = pms[((size_t)b * nblk + i) * 2];
    float s = pms[((size_t)b * nblk + i) * 2 + 1];
    float nm = fmaxf(M, m);
    S = S * __expf(M - nm) + s * __expf(m - nm);
    M = nm;
  }
  #pragma unroll
  for (int off = 32; off; off >>= 1) {
    float m2 = __shfl_xor(M, off), s2 = __shfl_xor(S, off);
    float nm = fmaxf(M, m2);
    S = S * __expf(M - nm) + s2 * __expf(m2 - nm);
    M = nm;
  }
  if ((t & 63) == 0) { sm[t >> 6] = M; ss[t >> 6] = S; }
  __syncthreads();
  if (t == 0) {
    float Mf = sm[0], Sf = ss[0];
    #pragma unroll
    for (int i = 1; i < 4; ++i) {
      float nm = fmaxf(Mf, sm[i]);
      Sf = Sf * __expf(Mf - nm) + ss[i] * __expf(sm[i] - nm);
      Mf = nm;
    }
    cbuf[b] = Mf + logf(Sf);
  }
}

// ------------- log_softmax subtract -------------
#define SL_ 6283
__global__ __launch_bounds__(256) void k_lsub(
    float* __restrict__ logits, const float* __restrict__ cbuf)
{
  int b = blockIdx.x, sl = blockIdx.y, t = threadIdx.x;
  float c = cbuf[b];
  int v0 = sl * SL_;
  int v1 = v0 + SL_; if (v1 > V_) v1 = V_;
  float* row = logits + (size_t)b * V_;
  for (int v = v0 + t; v < v1; v += 256) row[v] -= c;
}

extern "C" void kernel_launch(void* const* d_in, const int* in_sizes, int n_in,
                              void* d_out, int out_size, void* d_ws, size_t ws_size,
                              hipStream_t stream)
{
  const int*   input  = (const int*)d_in[0];
  const float* hidden = (const float*)d_in[1];
  const float* enc    = (const float*)d_in[2];
  const float* emb    = (const float*)d_in[3];
  const float* attn_W = (const float*)d_in[4];
  const float* attn_b = (const float*)d_in[5];
  const float* comb_W = (const float*)d_in[6];
  const float* comb_b = (const float*)d_in[7];
  const float* W_ih   = (const float*)d_in[8];
  const float* W_hh   = (const float*)d_in[9];
  const float* b_ih   = (const float*)d_in[10];
  const float* b_hh   = (const float*)d_in[11];
  const float* out_W  = (const float*)d_in[12];
  const float* out_b  = (const float*)d_in[13];

  float* out    = (float*)d_out;
  float* logits = out;                        // [B,V]
  float* hnew   = out + (size_t)B_ * V_;      // [1,B,H]
  float* attnw  = hnew + (size_t)B_ * H_;     // [B,L]

  const int NBLK = (V_ + 63) / 64;            // 786
  char* ws = (char*)d_ws;
  unsigned short* aXa = (unsigned short*)(ws);                 // 512K
  unsigned short* aH  = (unsigned short*)(ws + 524288);        // 256K
  unsigned short* aX  = (unsigned short*)(ws + 786432);        // 256K
  unsigned short* aHn = (unsigned short*)(ws + 1048576);       // 256K
  float* wbuf  = (float*)(ws + 1310720);                       // 32K
  float* lbuf  = (float*)(ws + 1343488);                       // 32K
  float* cbuf  = (float*)(ws + 1376256);                       // 4K
  float* pms   = (float*)(ws + 1380352);                       // 786K
  float* combP = (float*)(ws + 2185216);                       // 4MB  (8 splits)
  float* giP   = (float*)(ws + 6379520);                       // 6MB  (4 splits)
  float* ghP   = (float*)(ws + 12670976);                      // 6MB  (4 splits)

  // 1. pack embedded + hidden
  k_embh<<<512, 256, 0, stream>>>(input, hidden, emb, aXa, aH);
  // 2. attention logits (wave per (b,l))
  k_alog<<<(B_ * L_) / 4, 256, 0, stream>>>(input, hidden, emb, attn_W, attn_b, lbuf);
  // 3. attention softmax
  k_asm<<<B_ / 4, 256, 0, stream>>>(lbuf, attnw, wbuf);
  // 4. attention weighted sum; pack into aXa hi
  k_app<<<dim3(B_, 4), 256, 0, stream>>>(enc, wbuf, aXa);
  // 5. combine GEMM: K=2048 (64 chunks), 8 splits x 8 chunks
  k_gemm<<<dim3(16, 8), 256, 0, stream>>>(aXa, nullptr, comb_W, nullptr, nullptr,
                                          nullptr, combP, nullptr, nullptr,
                                          2 * H_, H_, 8, 0, 0);
  // 6. reduce + bias + relu -> packed x
  k_reduce_comb<<<(B_ * H_) / 256, 256, 0, stream>>>(combP, comb_b, aX);
  // 7. fused gi|gh GEMMs: K=1024 (32 chunks), each 4 splits x 8 chunks
  k_gemm<<<dim3(48, 8), 256, 0, stream>>>(aX, aH, W_ih, W_hh, nullptr,
                                          nullptr, giP, ghP, nullptr,
                                          H_, 3 * H_, 8, 4, 0);
  // 8. gates -> h_new (out) + packed h_new
  k_gate<<<(B_ * H_) / 256, 256, 0, stream>>>(giP, ghP, b_ih, b_hh, hidden, hnew, aHn);
  // 9. projection + bias + softmax partials (K=1024 -> 32 chunks, no split)
  k_gemm<<<dim3(NBLK, 1), 256, 0, stream>>>(aHn, nullptr, out_W, nullptr, out_b,
                                            logits, nullptr, nullptr, pms,
                                            H_, V_, 32, 0, NBLK);
  // 10. combine softmax partials -> per-row constant
  k_lsmr<<<B_, 256, 0, stream>>>(pms, cbuf, NBLK);
  // 11. subtract
  k_lsub<<<dim3(B_, 8), 256, 0, stream>>>(logits, cbuf);
}